// Round 8
// baseline (521.239 us; speedup 1.0000x reference)
//
#include <hip/hip_runtime.h>
#include <hip/hip_bf16.h>

// Shapes (fixed by the problem)
#define NB 2
#define NN 4096
#define NC 1024
#define NH 16
#define ND 64
#define NM (NB*NN)          // 8192 rows
#define NK 1024             // inner dim of both GEMMs
#define J_QKV 3072
// D^-0.5 * log2(e): folded into q at LN time so softmax runs in exp2 domain.
// Post-LN rows have ||q||,||k|| <= 8  =>  |score_exp2| <= 8*8*0.1803 = 11.54,
// so exp2(score) in [2^-11.6, 2^11.6]: fp32-safe with NO max subtraction.
#define QSCALE 0.18033688011112042f

typedef unsigned short u16;
typedef unsigned int   u32;
typedef __attribute__((ext_vector_type(8)))  __bf16 bf16x8;
typedef __attribute__((ext_vector_type(4)))  float  f32x4;
typedef __attribute__((ext_vector_type(16))) float  f32x16;

__device__ __forceinline__ float bf2f(u16 u) {
    unsigned int i = ((unsigned int)u) << 16;
    return __builtin_bit_cast(float, i);
}
__device__ __forceinline__ u16 f2bf(float f) {
    unsigned int i = __builtin_bit_cast(unsigned int, f);
    unsigned int lsb = (i >> 16) & 1u;
    i += 0x7fffu + lsb;          // RNE
    return (u16)(i >> 16);
}
__device__ __forceinline__ float fast_exp2(float x) {
#if __has_builtin(__builtin_amdgcn_exp2f)
    return __builtin_amdgcn_exp2f(x);   // v_exp_f32 = 2^x
#else
    return exp2f(x);
#endif
}
// Pack two f32 into one bf16x2 dword (v_cvt_pk_bf16_f32), RNE-equivalent.
#if __has_builtin(__builtin_amdgcn_cvt_pk_bf16_f32)
typedef __attribute__((ext_vector_type(2))) __bf16 bf16x2;
__device__ __forceinline__ u32 pk_bf16(float p0, float p1) {
    return __builtin_bit_cast(u32, __builtin_amdgcn_cvt_pk_bf16_f32(p0, p1));
}
#else
__device__ __forceinline__ u32 pk_bf16(float p0, float p1) {
    return (u32)f2bf(p0) | ((u32)f2bf(p1) << 16);
}
#endif

// DPP-based cross-lane sum over each 32-lane half (4 DPP + 1 ds_swizzle xor16).
template<int CTRL>
__device__ __forceinline__ float dppf(float x) {
    int r = __builtin_amdgcn_update_dpp(0, __builtin_bit_cast(int, x), CTRL, 0xF, 0xF, true);
    return __builtin_bit_cast(float, r);
}
__device__ __forceinline__ float swz16(float x) {
    int y = __builtin_amdgcn_ds_swizzle(__builtin_bit_cast(int, x), 0x401F); // xor 16
    return __builtin_bit_cast(float, y);
}
__device__ __forceinline__ float rsum32(float x) {
    x += dppf<0xB1>(x);     // quad_perm xor1
    x += dppf<0x4E>(x);     // quad_perm xor2
    x += dppf<0x124>(x);    // row_ror:4
    x += dppf<0x128>(x);    // row_ror:8
    return x + swz16(x);
}

// Async global->LDS 16B copy (global_load_lds_dwordx4).
__device__ __forceinline__ void glds16(const u16* g, u16* l) {
    __builtin_amdgcn_global_load_lds(
        (const __attribute__((address_space(1))) u32*)g,
        (__attribute__((address_space(3))) u32*)l, 16, 0, 0);
}

// ---------------------------------------------------------------------------
// fp32 -> bf16 elementwise convert (n multiple of 2048; 8 elems/thread).
// ---------------------------------------------------------------------------
__global__ __launch_bounds__(256) void cvt_bf16(
    const float* __restrict__ in, u16* __restrict__ out)
{
    const size_t i = ((size_t)blockIdx.x * 256 + threadIdx.x) * 8;
    const float4 a = *(const float4*)(in + i);
    const float4 b = *(const float4*)(in + i + 4);
    union { u16 h[8]; uint4 v; } u;
    u.h[0] = f2bf(a.x); u.h[1] = f2bf(a.y); u.h[2] = f2bf(a.z); u.h[3] = f2bf(a.w);
    u.h[4] = f2bf(b.x); u.h[5] = f2bf(b.y); u.h[6] = f2bf(b.z); u.h[7] = f2bf(b.w);
    *(uint4*)(out + i) = u.v;
}

// ---------------------------------------------------------------------------
// NT GEMM, m97 recipe: 128x128 tile, BK=32, global_load_lds(16B), 4 waves,
// each wave a 64x64 quadrant (4x4 grid of 16x16x32 MFMA tiles).
// MODE 0: fused per-head LayerNorm (q scaled by QSCALE) + scatter bf16 to
//         qkv ws [3][B][H][N][D].  Each wave's 64-col half == one head.
// MODE 1: fp32 linear [m][1024] (final output).
// ---------------------------------------------------------------------------
template<int MODE>
__global__ __launch_bounds__(256) void gemm_nt(
    const u16* __restrict__ A, const u16* __restrict__ W,
    const float* __restrict__ bias,
    const float* __restrict__ qw, const float* __restrict__ qb,
    const float* __restrict__ kw, const float* __restrict__ kb,
    void* __restrict__ outv)
{
    __shared__ __align__(16) u16 As[128][32];   // 8 KB
    __shared__ __align__(16) u16 Bs[128][32];   // 8 KB
    const int t = threadIdx.x;
    const int w = t >> 6, lane = t & 63;
    const int jb = blockIdx.x * 128;
    const int m0 = blockIdx.y * 128;
    const int wr = (w >> 1) * 64, wc = (w & 1) * 64;
    const int srow = t >> 2, skc = (t & 3) * 8;
    const u16* ap0 = A + (size_t)(m0 + srow) * NK + skc;
    const u16* ap1 = ap0 + (size_t)64 * NK;
    const u16* wp0 = W + (size_t)(jb + srow) * NK + skc;
    const u16* wp1 = wp0 + (size_t)64 * NK;
    u16* as0 = &As[srow][skc];      u16* as1 = &As[srow + 64][skc];
    u16* bs0 = &Bs[srow][skc];      u16* bs1 = &Bs[srow + 64][skc];
    const int fm = lane & 15, fk = 8 * (lane >> 4);
    f32x4 acc[4][4];
    #pragma unroll
    for (int i = 0; i < 4; ++i)
        #pragma unroll
        for (int j = 0; j < 4; ++j) acc[i][j] = (f32x4){0.f, 0.f, 0.f, 0.f};

    for (int kt = 0; kt < NK / 32; ++kt) {
        const int ko = kt * 32;
        glds16(ap0 + ko, as0);
        glds16(ap1 + ko, as1);
        glds16(wp0 + ko, bs0);
        glds16(wp1 + ko, bs1);
        __syncthreads();               // drains vmcnt (glds) before reads
        bf16x8 af[4], bfr[4];
        #pragma unroll
        for (int i = 0; i < 4; ++i) af[i]  = *(const bf16x8*)&As[wr + 16 * i + fm][fk];
        #pragma unroll
        for (int j = 0; j < 4; ++j) bfr[j] = *(const bf16x8*)&Bs[wc + 16 * j + fm][fk];
        #pragma unroll
        for (int i = 0; i < 4; ++i)
            #pragma unroll
            for (int j = 0; j < 4; ++j)
                acc[i][j] = __builtin_amdgcn_mfma_f32_16x16x32_bf16(af[i], bfr[j], acc[i][j], 0, 0, 0);
        __syncthreads();               // WAR before next kt's glds
    }
    // ---- epilogue ----
    const int c16 = lane & 15;
    float bv[4];
    #pragma unroll
    for (int j = 0; j < 4; ++j) bv[j] = bias[jb + wc + 16 * j + c16];
    #pragma unroll
    for (int i = 0; i < 4; ++i)
        #pragma unroll
        for (int j = 0; j < 4; ++j)
            #pragma unroll
            for (int r = 0; r < 4; ++r) acc[i][j][r] += bv[j];
    if (MODE == 0) {
        const int s = jb >> 10;            // 0=q, 1=k, 2=v (uniform per block)
        if (s < 2) {
            const float* lw = s ? kw : qw;
            const float* lb = s ? kb : qb;
            float lwv[4], lbv[4];
            #pragma unroll
            for (int j = 0; j < 4; ++j) {
                lwv[j] = lw[16 * j + c16]; lbv[j] = lb[16 * j + c16];
            }
            #pragma unroll
            for (int i = 0; i < 4; ++i)
                #pragma unroll
                for (int r = 0; r < 4; ++r) {
                    float sum = acc[i][0][r] + acc[i][1][r] + acc[i][2][r] + acc[i][3][r];
                    #pragma unroll
                    for (int off = 1; off < 16; off <<= 1) sum += __shfl_xor(sum, off);
                    const float mu = sum * (1.0f / 64.0f);
                    float v2 = 0.f;
                    #pragma unroll
                    for (int j = 0; j < 4; ++j) { const float dd = acc[i][j][r] - mu; v2 += dd * dd; }
                    #pragma unroll
                    for (int off = 1; off < 16; off <<= 1) v2 += __shfl_xor(v2, off);
                    const float rstd = rsqrtf(v2 * (1.0f / 64.0f) + 1e-5f);
                    #pragma unroll
                    for (int j = 0; j < 4; ++j) {
                        float y = (acc[i][j][r] - mu) * rstd * lwv[j] + lbv[j];
                        if (s == 0) y *= QSCALE;
                        acc[i][j][r] = y;
                    }
                }
        }
        u16* out = (u16*)outv;
        const int r0 = 4 * (lane >> 4);
        #pragma unroll
        for (int j = 0; j < 4; ++j) {
            const int col = jb + wc + 16 * j + c16;
            const int ss = col >> 10, hh = (col >> 6) & 15, d = col & 63;
            #pragma unroll
            for (int i = 0; i < 4; ++i)
                #pragma unroll
                for (int r = 0; r < 4; ++r) {
                    const int row = m0 + wr + 16 * i + r0 + r;
                    const int b = row >> 12, n = row & 4095;
                    out[((((size_t)ss * NB + b) * NH + hh) * NN + n) * ND + d] = f2bf(acc[i][j][r]);
                }
        }
    } else {
        float* out = (float*)outv;
        const int r0 = 4 * (lane >> 4);
        #pragma unroll
        for (int i = 0; i < 4; ++i)
            #pragma unroll
            for (int r = 0; r < 4; ++r) {
                const int row = m0 + wr + 16 * i + r0 + r;
                #pragma unroll
                for (int j = 0; j < 4; ++j)
                    out[(size_t)row * NC + jb + wc + 16 * j + c16] = acc[i][j][r];
            }
    }
}

// ---------------------------------------------------------------------------
// MFMA flash attention, fixed-shift softmax. Block = 4 waves; wave = 64 q-rows.
// 128-key staging per barrier pair, two 64-key compute sub-blocks.
// Key-permutation pi(c) = (c&1)*32 + (c>>1) applied consistently to P columns
// and Vt columns => P-store is one packed ds_write_b32 per 2 keys.
// Zero-C MFMA for the first k-step (no per-iter accumulator zero-init).
// 32x32x16 bf16. C/D: col=lane&31, row=(reg&3)+8*(reg>>2)+4*(lane>>5).
// ---------------------------------------------------------------------------
__global__ __launch_bounds__(256) void attn_mfma(
    const u16* __restrict__ qkv, u16* __restrict__ aout)
{
    __shared__ __align__(16) u16 Ks[128][72];     // K 128 keys [key][d]   18.4 KB
    __shared__ __align__(16) u16 Vt[64][136];     // V^T [d][pi-col, 2 sub] 17.4 KB
    __shared__ __align__(16) u16 Ps[4][64][72];   // per-wave P [q64][pi-col] 36.9 KB
    const int bid  = blockIdx.x;
    const int qblk = bid & 15;
    const int bh   = bid >> 4;
    const int b = bh >> 4, hh = bh & 15;
    const size_t plane = (size_t)NB * NH * NN * ND;
    const size_t base  = ((size_t)(b * NH + hh)) * NN * ND;
    const u16* qp = qkv + base;
    const u16* kp = qkv + plane + base;
    const u16* vp = qkv + 2 * plane + base;
    const int t = threadIdx.x, w = t >> 6, lane = t & 63;
    const int half = lane >> 5, m32 = lane & 31;
    const int q0 = qblk * 256 + 64 * w;           // this wave's 64 q-rows

    // Q A-frags for both 32-row sets; set s rows q0+32s+m32
    bf16x8 qf[2][4];
    #pragma unroll
    for (int s = 0; s < 2; ++s) {
        const u16* qrow = qp + (size_t)(q0 + 32 * s + m32) * ND + 8 * half;
        #pragma unroll
        for (int kt = 0; kt < 4; ++kt) qf[s][kt] = *(const bf16x8*)(qrow + 16 * kt);
    }
    f32x16 O[2][2];
    float l_r[2][16];
    #pragma unroll
    for (int s = 0; s < 2; ++s)
        #pragma unroll
        for (int r = 0; r < 16; ++r) { O[s][0][r] = 0.f; O[s][1][r] = 0.f; l_r[s][r] = 0.f; }
    f32x16 zc;                                    // loop-invariant zero C operand
    #pragma unroll
    for (int r = 0; r < 16; ++r) zc[r] = 0.f;

    const int krow = t & 127, kdc = (t >> 7) * 32;  // K staging: 2 thr/key, 32 d each
    const int vkey = t & 31,  vdg = (t >> 5) * 8;   // V staging: keys (j, j+32), 8 d

    for (int kb = 0; kb < NN / 128; ++kb) {
        const int kbase = kb * 128;
        __syncthreads();
        {   // stage K [key][d], 128 keys
            const u16* src = kp + (size_t)(kbase + krow) * ND + kdc;
            #pragma unroll
            for (int i = 0; i < 4; ++i)
                *(uint4*)&Ks[krow][kdc + 8 * i] = *(const uint4*)(src + 8 * i);
        }
        {   // stage V^T [d][pi-col]: pack key j (low u16) with key j+32 (high)
            #pragma unroll
            for (int s = 0; s < 2; ++s) {
                const u16* se = vp + (size_t)(kbase + 64 * s + vkey) * ND + vdg;
                union { uint4 v; u16 h[8]; } e, o;
                e.v = *(const uint4*)se;
                o.v = *(const uint4*)(se + 32 * ND);
                #pragma unroll
                for (int i = 0; i < 8; ++i) {
                    u32 pk = (u32)e.h[i] | ((u32)o.h[i] << 16);
                    *(u32*)&Vt[vdg + i][64 * s + 2 * vkey] = pk;
                }
            }
        }
        __syncthreads();
        #pragma unroll
        for (int s = 0; s < 2; ++s) {
            const int ks0 = 64 * s;
            // S = Q.K^T : 4 tiles (2 q-sets x 2 key-halves); zero-C on kt=0
            f32x16 sA0, sA1, sB0, sB1;
            #pragma unroll
            for (int kt = 0; kt < 4; ++kt) {
                bf16x8 k0 = *(const bf16x8*)&Ks[ks0 + m32][16 * kt + 8 * half];
                bf16x8 k1 = *(const bf16x8*)&Ks[ks0 + 32 + m32][16 * kt + 8 * half];
                sA0 = __builtin_amdgcn_mfma_f32_32x32x16_bf16(qf[0][kt], k0, kt ? sA0 : zc, 0, 0, 0);
                sA1 = __builtin_amdgcn_mfma_f32_32x32x16_bf16(qf[0][kt], k1, kt ? sA1 : zc, 0, 0, 0);
                sB0 = __builtin_amdgcn_mfma_f32_32x32x16_bf16(qf[1][kt], k0, kt ? sB0 : zc, 0, 0, 0);
                sB1 = __builtin_amdgcn_mfma_f32_32x32x16_bf16(qf[1][kt], k1, kt ? sB1 : zc, 0, 0, 0);
            }
            // fixed-shift softmax: p = exp2(s); packed pi-ordered P store
            #pragma unroll
            for (int r = 0; r < 16; ++r) {
                const int row = (r & 3) + 8 * (r >> 2) + 4 * half;
                const float a0 = fast_exp2(sA0[r]);
                const float a1 = fast_exp2(sA1[r]);
                l_r[0][r] += a0 + a1;
                *(u32*)&Ps[w][row][2 * m32] = pk_bf16(a0, a1);
                const float b0 = fast_exp2(sB0[r]);
                const float b1 = fast_exp2(sB1[r]);
                l_r[1][r] += b0 + b1;
                *(u32*)&Ps[w][32 + row][2 * m32] = pk_bf16(b0, b1);
            }
            // O += P.V (pi cancels between P cols and Vt cols; wave-private Ps)
            #pragma unroll
            for (int kt = 0; kt < 4; ++kt) {
                bf16x8 v0  = *(const bf16x8*)&Vt[m32][ks0 + 16 * kt + 8 * half];
                bf16x8 v1  = *(const bf16x8*)&Vt[32 + m32][ks0 + 16 * kt + 8 * half];
                bf16x8 pf0 = *(const bf16x8*)&Ps[w][m32][16 * kt + 8 * half];
                bf16x8 pf1 = *(const bf16x8*)&Ps[w][32 + m32][16 * kt + 8 * half];
                O[0][0] = __builtin_amdgcn_mfma_f32_32x32x16_bf16(pf0, v0, O[0][0], 0, 0, 0);
                O[0][1] = __builtin_amdgcn_mfma_f32_32x32x16_bf16(pf0, v1, O[0][1], 0, 0, 0);
                O[1][0] = __builtin_amdgcn_mfma_f32_32x32x16_bf16(pf1, v0, O[1][0], 0, 0, 0);
                O[1][1] = __builtin_amdgcn_mfma_f32_32x32x16_bf16(pf1, v1, O[1][1], 0, 0, 0);
            }
        }
    }
    // epilogue: reduce l across the row's 32 lanes, then out[b, n, hh*64 + d]
    #pragma unroll
    for (int s = 0; s < 2; ++s)
        #pragma unroll
        for (int r = 0; r < 16; ++r) {
            const float inv = 1.0f / rsum32(l_r[s][r]);
            const int row = q0 + 32 * s + (r & 3) + 8 * (r >> 2) + 4 * half;
            u16* dst = aout + ((size_t)(b * NN + row)) * NC + hh * 64;
            dst[m32]      = f2bf(O[s][0][r] * inv);
            dst[32 + m32] = f2bf(O[s][1][r] * inv);
        }
}

// ---------------------------------------------------------------------------
extern "C" void kernel_launch(void* const* d_in, const int* in_sizes, int n_in,
                              void* d_out, int out_size, void* d_ws, size_t ws_size,
                              hipStream_t stream) {
    const float* x     = (const float*)d_in[0];
    const float* qkv_w = (const float*)d_in[1];
    const float* qkv_b = (const float*)d_in[2];
    const float* q_nw  = (const float*)d_in[3];
    const float* q_nb  = (const float*)d_in[4];
    const float* k_nw  = (const float*)d_in[5];
    const float* k_nb  = (const float*)d_in[6];
    const float* p_w   = (const float*)d_in[7];
    const float* p_b   = (const float*)d_in[8];
    float* out = (float*)d_out;               // fp32 output
    // ws layout (u16 elements):
    //   qkv   [3][B][H][N][D]                              48 MB
    //   x_bf / attn_o (aliased: x_bf dead after QKV GEMM)  16.8 MB
    //   w_bf  qkv_w bf16                                    6.3 MB
    //   pw_bf proj_w bf16                                   2.1 MB
    u16* qkv    = (u16*)d_ws;
    u16* x_bf   = qkv + (size_t)3 * NB * NH * NN * ND;
    u16* attn_o = x_bf;                        // alias
    u16* w_bf   = x_bf + (size_t)NM * NC;
    u16* pw_bf  = w_bf + (size_t)J_QKV * NK;

    cvt_bf16<<<(NM * NC) / 2048, 256, 0, stream>>>(x, x_bf);
    cvt_bf16<<<(J_QKV * NK) / 2048, 256, 0, stream>>>(qkv_w, w_bf);
    cvt_bf16<<<(NC * NK) / 2048, 256, 0, stream>>>(p_w, pw_bf);

    gemm_nt<0><<<dim3(J_QKV / 128, NM / 128), 256, 0, stream>>>(
        x_bf, w_bf, qkv_b, q_nw, q_nb, k_nw, k_nb, qkv);
    attn_mfma<<<NB * NH * (NN / 256), 256, 0, stream>>>(qkv, attn_o);
    gemm_nt<1><<<dim3(NC / 128, NM / 128), 256, 0, stream>>>(
        attn_o, pw_bf, p_b, q_nw, q_nb, k_nw, k_nb, out);
}